// Round 4
// baseline (177.751 us; speedup 1.0000x reference)
//
#include <hip/hip_runtime.h>

#define NB 16
#define CD 128
#define HD 64
#define WD 64
#define SD 4096   // H*W
#define K7 896    // 7*C
#define XROW 72   // padded row stride of xT (3 zero | 64 data | 5 zero)

typedef float  f32x4  __attribute__((ext_vector_type(4)));
typedef __bf16 bf16x8 __attribute__((ext_vector_type(8)));
typedef __bf16 bf16x4 __attribute__((ext_vector_type(4)));

// ---------------------------------------------------------------------------
// prep: x (f32) -> xbf (bf16), 8 elems/thread
// ---------------------------------------------------------------------------
__global__ __launch_bounds__(256)
void cvt_x_kernel(const float* __restrict__ x, __bf16* __restrict__ xbf) {
  const int idx = (blockIdx.x * 256 + threadIdx.x) * 8;
  const float4 a = *(const float4*)(x + idx);
  const float4 b = *(const float4*)(x + idx + 4);
  bf16x8 v;
  v[0] = (__bf16)a.x; v[1] = (__bf16)a.y; v[2] = (__bf16)a.z; v[3] = (__bf16)a.w;
  v[4] = (__bf16)b.x; v[5] = (__bf16)b.y; v[6] = (__bf16)b.z; v[7] = (__bf16)b.w;
  *(bf16x8*)(xbf + idx) = v;
}

// ---------------------------------------------------------------------------
// prep: w7t[qmajor(k2)][k'] = bf16(w7[k'][k2]),  qmajor(c2*7+q) = q*128+c2
// ---------------------------------------------------------------------------
__global__ __launch_bounds__(256)
void w7t_kernel(const float* __restrict__ w7, __bf16* __restrict__ w7t) {
  __shared__ __bf16 tile[64][65];
  const int b2 = blockIdx.x * 64;   // k2 base
  const int bp = blockIdx.y * 64;   // k' base
  const int t  = threadIdx.x;
  const int col = t & 63;
  const int r0  = t >> 6;
#pragma unroll
  for (int rr = 0; rr < 16; ++rr) {
    const int row = rr * 4 + r0;
    tile[col][row] = (__bf16)w7[(size_t)(bp + row) * K7 + b2 + col];
  }
  __syncthreads();
#pragma unroll
  for (int rr = 0; rr < 16; ++rr) {
    const int row = rr * 4 + r0;
    const int k2  = b2 + row;
    const int c2  = k2 / 7, q = k2 - c2 * 7;
    w7t[(size_t)(q * 128 + c2) * K7 + bp + col] = tile[row][col];
  }
}

// ---------------------------------------------------------------------------
// prep: xT[n][i][j+3][c2] = xbf[n][c2][i][j], rows 0..2 & 67..71 zero
// ---------------------------------------------------------------------------
__global__ __launch_bounds__(256)
void xt_kernel(const __bf16* __restrict__ xbf, __bf16* __restrict__ xT) {
  __shared__ __bf16 tile[128][72];
  const int n = blockIdx.y;
  const int i = blockIdx.x;
  const int t = threadIdx.x;
  const __bf16* src = xbf + (size_t)n * CD * SD + (size_t)i * WD;
#pragma unroll
  for (int it = 0; it < 4; ++it) {
    const int c2 = it * 32 + (t >> 3);
    const int j  = (t & 7) * 8;
    *(bf16x8*)&tile[c2][j] = *(const bf16x8*)(src + (size_t)c2 * SD + j);
  }
  __bf16* dstn = xT + ((size_t)n * HD + i) * XROW * CD;
  if (t < 128) {  // zero-pad rows 0,1,2,67..71
    const int pr = t >> 4;
    const int rowz = pr < 3 ? pr : 64 + pr;
    bf16x8 z = {};
    *(bf16x8*)(dstn + (size_t)rowz * CD + (t & 15) * 8) = z;
  }
  __syncthreads();
#pragma unroll
  for (int it = 0; it < 4; ++it) {
    const int j   = t >> 2;
    const int c2b = (t & 3) * 32 + it * 8;
    bf16x8 v;
#pragma unroll
    for (int e = 0; e < 8; ++e) v[e] = tile[c2b + e][j];
    *(bf16x8*)(dstn + (size_t)(j + 3) * CD + c2b) = v;
  }
}

// ---------------------------------------------------------------------------
// MFMA GEMM 1 (split-K): partial T8 over s-chunk of NSTEP*32.
// ---------------------------------------------------------------------------
template<int NSTEP, bool PARTIAL>
__global__ __launch_bounds__(256)
void t8_mfma(const __bf16* __restrict__ xbf,
             const float* __restrict__ p2, const float* __restrict__ p3,
             float* __restrict__ part, __bf16* __restrict__ t8bf) {
  __shared__ __bf16 As[2][4 * 128 * 8];
  __shared__ __bf16 Bs[2][4 * 64 * 8];
  const int n  = blockIdx.z;
  const int kc = blockIdx.y;
  const int n0 = blockIdx.x * 64;
  const int sbase = kc * (NSTEP * 32);
  const int t = threadIdx.x;
  const int lane = t & 63, wid = t >> 6;
  const int wm = wid & 1, wn = wid >> 1;
  const int l16 = lane & 15, lg = lane >> 4;

  const __bf16* xbn = xbf + (size_t)n * CD * SD;
  const __bf16* a_src = xbn + (size_t)(t & 127) * SD + (t >> 7) * 8 + sbase;

  const int sg = t >> 6;
  const int kp = n0 + (t & 63);
  const int c2 = kp / 7, kk = kp - c2 * 7;
  const int drow = 2 * kk - 6;
  const __bf16* xpl = xbn + (size_t)c2 * SD + sg * 8;
  const float p3v = p3[kp];
  float g[2][8];
#pragma unroll
  for (int h2 = 0; h2 < 2; ++h2)
#pragma unroll
    for (int e = 0; e < 8; ++e)
      g[h2][e] = p3v * p2[c2 * WD + h2 * 32 + sg * 8 + e];

  int4 a0, a1;
  bf16x8 u = {};
  bool val;

#define T8_ISSUE(S0) do {                                              \
    a0 = *(const int4*)(a_src + ((S0) - sbase));                       \
    a1 = *(const int4*)(a_src + ((S0) - sbase) + 16);                  \
    const int ip_ = ((S0) >> 6) + drow;                                \
    val = ((unsigned)ip_ < (unsigned)HD);                              \
    if (val) u = *(const bf16x8*)(xpl + ip_ * WD + (((S0) >> 5) & 1) * 32); \
  } while (0)

#define T8_STAGE(B, H2) do {                                           \
    *(int4*)&As[B][(size_t)t * 8]         = a0;                        \
    *(int4*)&As[B][(size_t)(t + 256) * 8] = a1;                        \
    bf16x8 bv;                                                         \
    _Pragma("unroll")                                                  \
    for (int e = 0; e < 8; ++e)                                        \
      bv[e] = val ? (__bf16)((float)u[e] * g[H2][e]) : (__bf16)0.f;    \
    *(bf16x8*)&Bs[B][(size_t)t * 8] = bv;                              \
  } while (0)

  T8_ISSUE(sbase);
  T8_STAGE(0, (sbase >> 5) & 1);

  f32x4 acc[4][2] = {};
  for (int st = 0; st < NSTEP; ++st) {
    __syncthreads();
    const int cur = st & 1;
    const int s0n = sbase + (st + 1) * 32;
    if (st + 1 < NSTEP) T8_ISSUE(s0n);
    bf16x8 af[4], bfr[2];
#pragma unroll
    for (int fm = 0; fm < 4; ++fm)
      af[fm] = *(const bf16x8*)&As[cur][(size_t)(lg * 128 + wm * 64 + fm * 16 + l16) * 8];
#pragma unroll
    for (int fn = 0; fn < 2; ++fn)
      bfr[fn] = *(const bf16x8*)&Bs[cur][(size_t)(lg * 64 + wn * 32 + fn * 16 + l16) * 8];
#pragma unroll
    for (int fm = 0; fm < 4; ++fm)
#pragma unroll
      for (int fn = 0; fn < 2; ++fn)
        acc[fm][fn] = __builtin_amdgcn_mfma_f32_16x16x32_bf16(af[fm], bfr[fn], acc[fm][fn], 0, 0, 0);
    if (st + 1 < NSTEP) T8_STAGE(cur ^ 1, (s0n >> 5) & 1);
  }
#undef T8_ISSUE
#undef T8_STAGE

  const int colb = n0 + wn * 32 + l16;
  if constexpr (PARTIAL) {
    float* pb = part + (size_t)kc * (NB * CD * K7) + (size_t)n * CD * K7;
#pragma unroll
    for (int fm = 0; fm < 4; ++fm)
#pragma unroll
      for (int r = 0; r < 4; ++r) {
        const int c1 = wm * 64 + fm * 16 + lg * 4 + r;
        float* orow = pb + (size_t)c1 * K7 + colb;
        orow[0]  = acc[fm][0][r];
        orow[16] = acc[fm][1][r];
      }
  } else {
#pragma unroll
    for (int fm = 0; fm < 4; ++fm)
#pragma unroll
      for (int r = 0; r < 4; ++r) {
        const int c1 = wm * 64 + fm * 16 + lg * 4 + r;
        __bf16* orow = t8bf + ((size_t)n * CD + c1) * K7 + colb;
        orow[0]  = (__bf16)(acc[fm][0][r] * (1.f / 64.f));
        orow[16] = (__bf16)(acc[fm][1][r] * (1.f / 64.f));
      }
  }
}

// ---------------------------------------------------------------------------
// reduce split-K partials -> bf16 with scale
// ---------------------------------------------------------------------------
template<int KC>
__global__ __launch_bounds__(256)
void reduce_scale(const float* __restrict__ part, __bf16* __restrict__ dst,
                  float scale) {
  const size_t idx = ((size_t)blockIdx.x * 256 + threadIdx.x) * 4;
  const size_t stride = (size_t)NB * CD * K7;
  float4 s = *(const float4*)(part + idx);
#pragma unroll
  for (int c = 1; c < KC; ++c) {
    const float4 p = *(const float4*)(part + c * stride + idx);
    s.x += p.x; s.y += p.y; s.z += p.z; s.w += p.w;
  }
  bf16x4 v;
  v[0] = (__bf16)(s.x * scale); v[1] = (__bf16)(s.y * scale);
  v[2] = (__bf16)(s.z * scale); v[3] = (__bf16)(s.w * scale);
  *(bf16x4*)(dst + idx) = v;
}

// ---------------------------------------------------------------------------
// MFMA GEMM 2 (split-K): M = (T8 (2048x896) * w7) / sqrt(896), q-major cols
// ---------------------------------------------------------------------------
template<int NSTEP, bool PARTIAL>
__global__ __launch_bounds__(256)
void m_mfma(const __bf16* __restrict__ t8bf, const __bf16* __restrict__ w7t,
            float* __restrict__ part, __bf16* __restrict__ mmbf) {
  __shared__ __bf16 As[2][4 * 128 * 8];
  __shared__ __bf16 Bs[2][4 * 64 * 8];
  const int m0 = blockIdx.y * 128;
  const int n0 = blockIdx.x * 64;
  const int kc = blockIdx.z;
  const int koff = kc * (NSTEP * 32);
  const int t  = threadIdx.x;
  const int lane = t & 63, wid = t >> 6;
  const int wm = wid & 1, wn = wid >> 1;
  const int l16 = lane & 15, lg = lane >> 4;

  const __bf16* a_src = t8bf + (size_t)(m0 + (t & 127)) * K7 + (t >> 7) * 8 + koff;
  const __bf16* b_src = w7t + (size_t)(n0 + (t & 63)) * K7 + (t >> 6) * 8 + koff;

  int4 a0 = *(const int4*)a_src;
  int4 a1 = *(const int4*)(a_src + 16);
  int4 b0 = *(const int4*)b_src;
  *(int4*)&As[0][(size_t)t * 8]         = a0;
  *(int4*)&As[0][(size_t)(t + 256) * 8] = a1;
  *(int4*)&Bs[0][(size_t)t * 8]         = b0;

  f32x4 acc[4][2] = {};
  for (int st = 0; st < NSTEP; ++st) {
    __syncthreads();
    const int cur = st & 1;
    if (st + 1 < NSTEP) {
      a0 = *(const int4*)(a_src + (st + 1) * 32);
      a1 = *(const int4*)(a_src + (st + 1) * 32 + 16);
      b0 = *(const int4*)(b_src + (st + 1) * 32);
    }
    bf16x8 af[4], bfr[2];
#pragma unroll
    for (int fm = 0; fm < 4; ++fm)
      af[fm] = *(const bf16x8*)&As[cur][(size_t)(lg * 128 + wm * 64 + fm * 16 + l16) * 8];
#pragma unroll
    for (int fn = 0; fn < 2; ++fn)
      bfr[fn] = *(const bf16x8*)&Bs[cur][(size_t)(lg * 64 + wn * 32 + fn * 16 + l16) * 8];
#pragma unroll
    for (int fm = 0; fm < 4; ++fm)
#pragma unroll
      for (int fn = 0; fn < 2; ++fn)
        acc[fm][fn] = __builtin_amdgcn_mfma_f32_16x16x32_bf16(af[fm], bfr[fn], acc[fm][fn], 0, 0, 0);
    if (st + 1 < NSTEP) {
      *(int4*)&As[cur ^ 1][(size_t)t * 8]         = a0;
      *(int4*)&As[cur ^ 1][(size_t)(t + 256) * 8] = a1;
      *(int4*)&Bs[cur ^ 1][(size_t)t * 8]         = b0;
    }
  }
  const int colb = n0 + wn * 32 + l16;
  if constexpr (PARTIAL) {
    float* pb = part + (size_t)kc * (NB * CD * K7);
#pragma unroll
    for (int fm = 0; fm < 4; ++fm)
#pragma unroll
      for (int r = 0; r < 4; ++r) {
        const int mr = m0 + wm * 64 + fm * 16 + lg * 4 + r;
        float* orow = pb + (size_t)mr * K7 + colb;
        orow[0]  = acc[fm][0][r];
        orow[16] = acc[fm][1][r];
      }
  } else {
    const float sc = 0.033407655f;  // 1/sqrt(896)
#pragma unroll
    for (int fm = 0; fm < 4; ++fm)
#pragma unroll
      for (int r = 0; r < 4; ++r) {
        const int mr = m0 + wm * 64 + fm * 16 + lg * 4 + r;
        __bf16* orow = mmbf + (size_t)mr * K7 + colb;
        orow[0]  = (__bf16)(acc[fm][0][r] * sc);
        orow[16] = (__bf16)(acc[fm][1][r] * sc);
      }
  }
}

// ---------------------------------------------------------------------------
// MFMA GEMM 3: out[n,c,i*64+j] = sum_k M[n,c,k]*B[k][j] - t6
//   qmajor k: B[k][j] = xT[n,i,j+q,(k&127)] -> linear walk when XT
// ---------------------------------------------------------------------------
template<bool XT>
__global__ __launch_bounds__(256)
void out_mfma(const float* __restrict__ x, const __bf16* __restrict__ xbf,
              const __bf16* __restrict__ xT, const __bf16* __restrict__ mmbf,
              const float* __restrict__ p4, const float* __restrict__ w6,
              float* __restrict__ outp) {
  __shared__ __bf16 As[2][4 * 128 * 8];
  __shared__ __bf16 Bs[2][4 * 64 * 8];
  const int n = blockIdx.z;
  const int i = blockIdx.x;
  const int t = threadIdx.x;
  const int lane = t & 63, wid = t >> 6;
  const int wm = wid & 1, wn = wid >> 1;
  const int l16 = lane & 15, lg = lane >> 4;

  const __bf16* a_src = mmbf + (size_t)n * CD * K7 + (size_t)(t & 127) * K7 + (t >> 7) * 8;

  // XT path: sg = t&3, col = t>>2 (coalesced 64B groups); linear offset = k0
  const int b_sg  = t & 3;
  const int b_col = t >> 2;
  const __bf16* b_src = XT
    ? xT + (((size_t)n * HD + i) * XROW + b_col) * CD + b_sg * 8
    : nullptr;
  const int b_lds = (b_sg * 64 + b_col) * 8;

  // gather-fallback path
  const __bf16* xbn = xbf + (size_t)n * CD * SD;
  const int sg2 = t >> 6, scol = t & 63;

  int4 a0, a1;
  bf16x8 ub;

#define OUT_ISSUE(K0) do {                                             \
    a0 = *(const int4*)(a_src + (K0));                                 \
    a1 = *(const int4*)(a_src + (K0) + 16);                            \
    if constexpr (XT) {                                                \
      ub = *(const bf16x8*)(b_src + (K0));                             \
    } else {                                                           \
      _Pragma("unroll")                                                \
      for (int e = 0; e < 8; ++e) {                                    \
        const int k2 = (K0) + sg2 * 8 + e;                             \
        const int q_  = k2 >> 7;                                       \
        const int c2_ = k2 & 127;                                      \
        const int jp_ = scol + q_ - 3;                                 \
        ub[e] = ((unsigned)jp_ < (unsigned)WD)                         \
                  ? xbn[(size_t)c2_ * SD + i * WD + jp_] : (__bf16)0.f; \
      }                                                                \
    }                                                                  \
  } while (0)

#define OUT_STAGE(B) do {                                              \
    *(int4*)&As[B][(size_t)t * 8]         = a0;                        \
    *(int4*)&As[B][(size_t)(t + 256) * 8] = a1;                        \
    if constexpr (XT) { *(bf16x8*)&Bs[B][b_lds] = ub; }                \
    else             { *(bf16x8*)&Bs[B][(size_t)t * 8] = ub; }         \
  } while (0)

  OUT_ISSUE(0);
  OUT_STAGE(0);

  f32x4 acc[4][2] = {};
  const int NSTEP = K7 / 32;
  for (int st = 0; st < NSTEP; ++st) {
    __syncthreads();
    const int cur = st & 1;
    if (st + 1 < NSTEP) OUT_ISSUE((st + 1) * 32);
    bf16x8 af[4], bfr[2];
#pragma unroll
    for (int fm = 0; fm < 4; ++fm)
      af[fm] = *(const bf16x8*)&As[cur][(size_t)(lg * 128 + wm * 64 + fm * 16 + l16) * 8];
#pragma unroll
    for (int fn = 0; fn < 2; ++fn)
      bfr[fn] = *(const bf16x8*)&Bs[cur][(size_t)(lg * 64 + wn * 32 + fn * 16 + l16) * 8];
#pragma unroll
    for (int fm = 0; fm < 4; ++fm)
#pragma unroll
      for (int fn = 0; fn < 2; ++fn)
        acc[fm][fn] = __builtin_amdgcn_mfma_f32_16x16x32_bf16(af[fm], bfr[fn], acc[fm][fn], 0, 0, 0);
    if (st + 1 < NSTEP) OUT_STAGE(cur ^ 1);
  }
#undef OUT_ISSUE
#undef OUT_STAGE

  const float* xn = x + (size_t)n * CD * SD;
#pragma unroll
  for (int fm = 0; fm < 4; ++fm)
#pragma unroll
    for (int r = 0; r < 4; ++r) {
      const int c = wm * 64 + fm * 16 + lg * 4 + r;
      const float w60 = w6[c * 3 + 0], w61 = w6[c * 3 + 1], w62 = w6[c * 3 + 2];
      const float* xc  = xn + (size_t)c * SD;
      const float* p4c = p4 + (size_t)c * SD;
#pragma unroll
      for (int fn = 0; fn < 2; ++fn) {
        const int j  = wn * 32 + fn * 16 + l16;
        const int jm = (j - 1) & 63;
        float t6 = w61 * p4c[i * WD + jm] * xc[i * WD + jm];
        if (i >= 3)  t6 += w60 * p4c[(i - 3) * WD + jm] * xc[(i - 3) * WD + jm];
        if (i <= 60) t6 += w62 * p4c[(i + 3) * WD + jm] * xc[(i + 3) * WD + jm];
        outp[((size_t)(n * CD + c)) * SD + i * WD + j] = acc[fm][fn][r] - t6;
      }
    }
}

extern "C" void kernel_launch(void* const* d_in, const int* in_sizes, int n_in,
                              void* d_out, int out_size, void* d_ws, size_t ws_size,
                              hipStream_t stream) {
  const float* x  = (const float*)d_in[0];
  const float* p2 = (const float*)d_in[1];
  const float* p3 = (const float*)d_in[2];
  const float* p4 = (const float*)d_in[3];
  const float* w6 = (const float*)d_in[4];
  const float* w7 = (const float*)d_in[5];
  float* outp = (float*)d_out;

  const size_t elems_x  = (size_t)NB * CD * SD;   // 8,388,608
  const size_t elems_t8 = (size_t)NB * CD * K7;   // 1,835,008

  __bf16* xbf  = (__bf16*)d_ws;
  __bf16* t8bf = xbf  + elems_x;
  __bf16* mmbf = t8bf + elems_t8;
  __bf16* w7t  = mmbf + elems_t8;
  void*   region = (void*)(w7t + (size_t)K7 * K7);  // part / xT (disjoint phases)
  float*  part = (float*)region;
  __bf16* xT   = (__bf16*)region;

  const size_t base_bytes = (elems_x + 2 * elems_t8 + (size_t)K7 * K7) * 2; // 25,722,880
  const size_t chunk      = elems_t8 * 4;                                   // 7,340,032
  const size_t xt_bytes   = (size_t)NB * HD * XROW * CD * 2;                // 18,874,368

  const bool split4 = ws_size >= base_bytes + 4 * chunk;
  const bool split2 = ws_size >= base_bytes + 2 * chunk;
  const bool use_xt = ws_size >= base_bytes + xt_bytes;

  dim3 blk(256);
  cvt_x_kernel<<<dim3((unsigned)(elems_x / (256 * 8))), blk, 0, stream>>>(x, xbf);
  w7t_kernel<<<dim3(14, 14), blk, 0, stream>>>(w7, w7t);

  if (split4) {
    t8_mfma<32, true><<<dim3(14, 4, NB), blk, 0, stream>>>(xbf, p2, p3, part, nullptr);
    reduce_scale<4><<<dim3((unsigned)(elems_t8 / 1024)), blk, 0, stream>>>(part, t8bf, 1.f / 64.f);
  } else if (split2) {
    t8_mfma<64, true><<<dim3(14, 2, NB), blk, 0, stream>>>(xbf, p2, p3, part, nullptr);
    reduce_scale<2><<<dim3((unsigned)(elems_t8 / 1024)), blk, 0, stream>>>(part, t8bf, 1.f / 64.f);
  } else {
    t8_mfma<128, false><<<dim3(14, 1, NB), blk, 0, stream>>>(xbf, p2, p3, nullptr, t8bf);
  }

  if (split2) {
    m_mfma<14, true><<<dim3(14, 16, 2), blk, 0, stream>>>(t8bf, w7t, part, nullptr);
    reduce_scale<2><<<dim3((unsigned)(elems_t8 / 1024)), blk, 0, stream>>>(part, mmbf, 0.033407655f);
  } else {
    m_mfma<28, false><<<dim3(14, 16, 1), blk, 0, stream>>>(t8bf, w7t, nullptr, mmbf);
  }

  if (use_xt) {
    xt_kernel<<<dim3(HD, NB), blk, 0, stream>>>(xbf, xT);
    out_mfma<true><<<dim3(HD, 1, NB), blk, 0, stream>>>(x, xbf, xT, mmbf, p4, w6, outp);
  } else {
    out_mfma<false><<<dim3(HD, 1, NB), blk, 0, stream>>>(x, xbf, nullptr, mmbf, p4, w6, outp);
  }
}

// Round 5
// 170.133 us; speedup vs baseline: 1.0448x; 1.0448x over previous
//
#include <hip/hip_runtime.h>

#define NB 16
#define CD 128
#define HD 64
#define WD 64
#define SD 4096   // H*W
#define K7 896    // 7*C
#define XROW 72   // padded row stride of xT (3 zero | 64 data | 5 zero)

typedef float  f32x4  __attribute__((ext_vector_type(4)));
typedef __bf16 bf16x8 __attribute__((ext_vector_type(8)));
typedef __bf16 bf16x4 __attribute__((ext_vector_type(4)));

// ---------------------------------------------------------------------------
// prep: x (f32) -> xbf (bf16)
// ---------------------------------------------------------------------------
__global__ __launch_bounds__(256)
void cvt_x_kernel(const float* __restrict__ x, __bf16* __restrict__ xbf) {
  const int idx = (blockIdx.x * 256 + threadIdx.x) * 8;
  const float4 a = *(const float4*)(x + idx);
  const float4 b = *(const float4*)(x + idx + 4);
  bf16x8 v;
  v[0] = (__bf16)a.x; v[1] = (__bf16)a.y; v[2] = (__bf16)a.z; v[3] = (__bf16)a.w;
  v[4] = (__bf16)b.x; v[5] = (__bf16)b.y; v[6] = (__bf16)b.z; v[7] = (__bf16)b.w;
  *(bf16x8*)(xbf + idx) = v;
}

// ---------------------------------------------------------------------------
// prep: w7t[qmajor(k2)][k'] = bf16(w7[k'][k2]),  qmajor(c2*7+q) = q*128+c2
// ---------------------------------------------------------------------------
__global__ __launch_bounds__(256)
void w7t_kernel(const float* __restrict__ w7, __bf16* __restrict__ w7t) {
  __shared__ __bf16 tile[64][65];
  const int b2 = blockIdx.x * 64;   // k2 base
  const int bp = blockIdx.y * 64;   // k' base
  const int t  = threadIdx.x;
  const int col = t & 63;
  const int r0  = t >> 6;
#pragma unroll
  for (int rr = 0; rr < 16; ++rr) {
    const int row = rr * 4 + r0;
    tile[col][row] = (__bf16)w7[(size_t)(bp + row) * K7 + b2 + col];
  }
  __syncthreads();
#pragma unroll
  for (int rr = 0; rr < 16; ++rr) {
    const int row = rr * 4 + r0;
    const int k2  = b2 + row;
    const int c2  = k2 / 7, q = k2 - c2 * 7;
    w7t[(size_t)(q * 128 + c2) * K7 + bp + col] = tile[row][col];
  }
}

// ---------------------------------------------------------------------------
// prep: xT[n][i][j+3][c2] = xbf[n][c2][i][j], rows 0..2 & 67..71 zero
// ---------------------------------------------------------------------------
__global__ __launch_bounds__(256)
void xt_kernel(const __bf16* __restrict__ xbf, __bf16* __restrict__ xT) {
  __shared__ __bf16 tile[128][72];
  const int n = blockIdx.y;
  const int i = blockIdx.x;
  const int t = threadIdx.x;
  const __bf16* src = xbf + (size_t)n * CD * SD + (size_t)i * WD;
#pragma unroll
  for (int it = 0; it < 4; ++it) {
    const int c2 = it * 32 + (t >> 3);
    const int j  = (t & 7) * 8;
    *(bf16x8*)&tile[c2][j] = *(const bf16x8*)(src + (size_t)c2 * SD + j);
  }
  __bf16* dstn = xT + ((size_t)n * HD + i) * XROW * CD;
  if (t < 128) {  // zero-pad rows 0,1,2,67..71
    const int pr = t >> 4;
    const int rowz = pr < 3 ? pr : 64 + pr;
    bf16x8 z = {};
    *(bf16x8*)(dstn + (size_t)rowz * CD + (t & 15) * 8) = z;
  }
  __syncthreads();
#pragma unroll
  for (int it = 0; it < 4; ++it) {
    const int j   = t >> 2;
    const int c2b = (t & 3) * 32 + it * 8;
    bf16x8 v;
#pragma unroll
    for (int e = 0; e < 8; ++e) v[e] = tile[c2b + e][j];
    *(bf16x8*)(dstn + (size_t)(j + 3) * CD + c2b) = v;
  }
}

// ---------------------------------------------------------------------------
// MFMA GEMM 1 (split-K): T8 partial over s-chunk NSTEP*32.
// 128(M=c1) x 128(N=k') tile, BK=32, 4 waves (2x2), 2-deep prefetch.
// ---------------------------------------------------------------------------
template<int NSTEP, bool PARTIAL>
__global__ __launch_bounds__(256)
void t8_mfma(const __bf16* __restrict__ xbf,
             const float* __restrict__ p2, const float* __restrict__ p3,
             float* __restrict__ part, __bf16* __restrict__ t8bf) {
  __shared__ __bf16 As[2][4 * 128 * 8];
  __shared__ __bf16 Bs[2][4 * 128 * 8];
  const int n  = blockIdx.z;
  const int kc = blockIdx.y;
  const int n0 = blockIdx.x * 128;
  const int sbase = kc * (NSTEP * 32);
  const int t = threadIdx.x;
  const int lane = t & 63, wid = t >> 6;
  const int wm = wid & 1, wn = wid >> 1;
  const int l16 = lane & 15, lg = lane >> 4;

  const __bf16* xbn = xbf + (size_t)n * CD * SD;
  const __bf16* a_src = xbn + (size_t)(t & 127) * SD + (t >> 7) * 8 + sbase;

  const int kp  = n0 + (t & 127);
  const int sgA = t >> 7;
  const int c2 = kp / 7, kk = kp - c2 * 7;
  const int drow = 2 * kk - 6;
  const __bf16* xpl = xbn + (size_t)c2 * SD;
  const float p3v = p3[kp];
  float g[2][2][8];
#pragma unroll
  for (int h2 = 0; h2 < 2; ++h2)
#pragma unroll
    for (int sl = 0; sl < 2; ++sl)
#pragma unroll
      for (int e = 0; e < 8; ++e)
        g[h2][sl][e] = p3v * p2[c2 * WD + h2 * 32 + (sgA + 2 * sl) * 8 + e];

  int4 a0_0, a1_0, a0_1, a1_1;
  bf16x8 u0_0 = {}, u1_0 = {}, u0_1 = {}, u1_1 = {};
  bool val_0, val_1;

#define T8_ISSUE(ST, S) do {                                            \
    a0_##S = *(const int4*)(a_src + (ST) * 32);                         \
    a1_##S = *(const int4*)(a_src + (ST) * 32 + 16);                    \
    const int s0_ = sbase + (ST) * 32;                                  \
    const int ip_ = (s0_ >> 6) + drow;                                  \
    val_##S = ((unsigned)ip_ < (unsigned)HD);                           \
    const __bf16* br_ = xpl + ip_ * WD + ((s0_ >> 5) & 1) * 32 + sgA * 8; \
    if (val_##S) { u0_##S = *(const bf16x8*)br_;                        \
                   u1_##S = *(const bf16x8*)(br_ + 16); }               \
  } while (0)

#define T8_STAGE(B, S, H2) do {                                         \
    *(int4*)&As[B][(size_t)t * 8]         = a0_##S;                     \
    *(int4*)&As[B][(size_t)(t + 256) * 8] = a1_##S;                     \
    bf16x8 b0_, b1_;                                                    \
    _Pragma("unroll")                                                   \
    for (int e = 0; e < 8; ++e) {                                       \
      b0_[e] = val_##S ? (__bf16)((float)u0_##S[e] * g[H2][0][e]) : (__bf16)0.f; \
      b1_[e] = val_##S ? (__bf16)((float)u1_##S[e] * g[H2][1][e]) : (__bf16)0.f; \
    }                                                                   \
    *(bf16x8*)&Bs[B][(size_t)t * 8]         = b0_;                      \
    *(bf16x8*)&Bs[B][(size_t)(t + 256) * 8] = b1_;                      \
  } while (0)

#define GEMM_COMPUTE(B) do {                                            \
    bf16x8 af[4], bfr[4];                                               \
    _Pragma("unroll")                                                   \
    for (int fm = 0; fm < 4; ++fm)                                      \
      af[fm] = *(const bf16x8*)&As[B][(size_t)(lg * 128 + wm * 64 + fm * 16 + l16) * 8]; \
    _Pragma("unroll")                                                   \
    for (int fn = 0; fn < 4; ++fn)                                      \
      bfr[fn] = *(const bf16x8*)&Bs[B][(size_t)(lg * 128 + wn * 64 + fn * 16 + l16) * 8]; \
    _Pragma("unroll")                                                   \
    for (int fm = 0; fm < 4; ++fm)                                      \
      _Pragma("unroll")                                                 \
      for (int fn = 0; fn < 4; ++fn)                                    \
        acc[fm][fn] = __builtin_amdgcn_mfma_f32_16x16x32_bf16(af[fm], bfr[fn], acc[fm][fn], 0, 0, 0); \
  } while (0)

  f32x4 acc[4][4] = {};
  T8_ISSUE(0, 0); T8_STAGE(0, 0, 0); T8_ISSUE(1, 1);
  for (int st = 0; st < NSTEP; st += 2) {
    __syncthreads();
    if (st + 2 < NSTEP) T8_ISSUE(st + 2, 0);
    GEMM_COMPUTE(0);
    T8_STAGE(1, 1, 1);
    __syncthreads();
    if (st + 3 < NSTEP) T8_ISSUE(st + 3, 1);
    GEMM_COMPUTE(1);
    if (st + 2 < NSTEP) T8_STAGE(0, 0, 0);
  }
#undef T8_ISSUE
#undef T8_STAGE

  const int colb = n0 + wn * 64 + l16;
  if constexpr (PARTIAL) {
    float* pb = part + (size_t)kc * (NB * CD * K7) + (size_t)n * CD * K7;
#pragma unroll
    for (int fm = 0; fm < 4; ++fm)
#pragma unroll
      for (int r = 0; r < 4; ++r) {
        const int c1 = wm * 64 + fm * 16 + lg * 4 + r;
        float* orow = pb + (size_t)c1 * K7 + colb;
#pragma unroll
        for (int fn = 0; fn < 4; ++fn) orow[fn * 16] = acc[fm][fn][r];
      }
  } else {
#pragma unroll
    for (int fm = 0; fm < 4; ++fm)
#pragma unroll
      for (int r = 0; r < 4; ++r) {
        const int c1 = wm * 64 + fm * 16 + lg * 4 + r;
        __bf16* orow = t8bf + ((size_t)n * CD + c1) * K7 + colb;
#pragma unroll
        for (int fn = 0; fn < 4; ++fn)
          orow[fn * 16] = (__bf16)(acc[fm][fn][r] * (1.f / 64.f));
      }
  }
}

// ---------------------------------------------------------------------------
// reduce split-K partials -> bf16 with scale
// ---------------------------------------------------------------------------
template<int KC>
__global__ __launch_bounds__(256)
void reduce_scale(const float* __restrict__ part, __bf16* __restrict__ dst,
                  float scale) {
  const size_t idx = ((size_t)blockIdx.x * 256 + threadIdx.x) * 4;
  const size_t stride = (size_t)NB * CD * K7;
  float4 s = *(const float4*)(part + idx);
#pragma unroll
  for (int c = 1; c < KC; ++c) {
    const float4 p = *(const float4*)(part + c * stride + idx);
    s.x += p.x; s.y += p.y; s.z += p.z; s.w += p.w;
  }
  bf16x4 v;
  v[0] = (__bf16)(s.x * scale); v[1] = (__bf16)(s.y * scale);
  v[2] = (__bf16)(s.z * scale); v[3] = (__bf16)(s.w * scale);
  *(bf16x4*)(dst + idx) = v;
}

// ---------------------------------------------------------------------------
// MFMA GEMM 2 (split-K): M = (T8 (2048x896) * w7) / sqrt(896), q-major cols
// 128x128 tile, 2-deep prefetch.
// ---------------------------------------------------------------------------
template<int NSTEP, bool PARTIAL>
__global__ __launch_bounds__(256)
void m_mfma(const __bf16* __restrict__ t8bf, const __bf16* __restrict__ w7t,
            float* __restrict__ part, __bf16* __restrict__ mmbf) {
  __shared__ __bf16 As[2][4 * 128 * 8];
  __shared__ __bf16 Bs[2][4 * 128 * 8];
  const int m0 = blockIdx.y * 128;
  const int n0 = blockIdx.x * 128;
  const int kc = blockIdx.z;
  const int koff = kc * (NSTEP * 32);
  const int t  = threadIdx.x;
  const int lane = t & 63, wid = t >> 6;
  const int wm = wid & 1, wn = wid >> 1;
  const int l16 = lane & 15, lg = lane >> 4;

  const __bf16* a_src = t8bf + (size_t)(m0 + (t & 127)) * K7 + (t >> 7) * 8 + koff;
  const __bf16* b_src = w7t + (size_t)(n0 + (t & 127)) * K7 + (t >> 7) * 8 + koff;

  int4 a0_0, a1_0, a0_1, a1_1;
  int4 b0_0, b1_0, b0_1, b1_1;

#define M_ISSUE(ST, S) do {                                             \
    a0_##S = *(const int4*)(a_src + (ST) * 32);                         \
    a1_##S = *(const int4*)(a_src + (ST) * 32 + 16);                    \
    b0_##S = *(const int4*)(b_src + (ST) * 32);                         \
    b1_##S = *(const int4*)(b_src + (ST) * 32 + 16);                    \
  } while (0)

#define M_STAGE(B, S) do {                                              \
    *(int4*)&As[B][(size_t)t * 8]         = a0_##S;                     \
    *(int4*)&As[B][(size_t)(t + 256) * 8] = a1_##S;                     \
    *(int4*)&Bs[B][(size_t)t * 8]         = b0_##S;                     \
    *(int4*)&Bs[B][(size_t)(t + 256) * 8] = b1_##S;                     \
  } while (0)

  f32x4 acc[4][4] = {};
  M_ISSUE(0, 0); M_STAGE(0, 0); M_ISSUE(1, 1);
  for (int st = 0; st < NSTEP; st += 2) {
    __syncthreads();
    if (st + 2 < NSTEP) M_ISSUE(st + 2, 0);
    GEMM_COMPUTE(0);
    M_STAGE(1, 1);
    __syncthreads();
    if (st + 3 < NSTEP) M_ISSUE(st + 3, 1);
    GEMM_COMPUTE(1);
    if (st + 2 < NSTEP) M_STAGE(0, 0);
  }
#undef M_ISSUE
#undef M_STAGE

  const int colb = n0 + wn * 64 + l16;
  if constexpr (PARTIAL) {
    float* pb = part + (size_t)kc * (NB * CD * K7);
#pragma unroll
    for (int fm = 0; fm < 4; ++fm)
#pragma unroll
      for (int r = 0; r < 4; ++r) {
        const int mr = m0 + wm * 64 + fm * 16 + lg * 4 + r;
        float* orow = pb + (size_t)mr * K7 + colb;
#pragma unroll
        for (int fn = 0; fn < 4; ++fn) orow[fn * 16] = acc[fm][fn][r];
      }
  } else {
    const float sc = 0.033407655f;  // 1/sqrt(896)
#pragma unroll
    for (int fm = 0; fm < 4; ++fm)
#pragma unroll
      for (int r = 0; r < 4; ++r) {
        const int mr = m0 + wm * 64 + fm * 16 + lg * 4 + r;
        __bf16* orow = mmbf + (size_t)mr * K7 + colb;
#pragma unroll
        for (int fn = 0; fn < 4; ++fn)
          orow[fn * 16] = (__bf16)(acc[fm][fn][r] * sc);
      }
  }
}

// ---------------------------------------------------------------------------
// MFMA GEMM 3: out[n,c,i*64+j] = sum_k M[n,c,k]*B[k][col] - t6
// 128(M=c) x 128(N=2 image rows) tile, 2-deep prefetch, swizzled Bs.
// ---------------------------------------------------------------------------
template<bool XTP>
__global__ __launch_bounds__(256)
void out_mfma(const float* __restrict__ x, const __bf16* __restrict__ xbf,
              const __bf16* __restrict__ xT, const __bf16* __restrict__ mmbf,
              const float* __restrict__ p4, const float* __restrict__ w6,
              float* __restrict__ outp) {
  __shared__ __bf16 As[2][4 * 128 * 8];
  __shared__ __bf16 Bs[2][4 * 128 * 8];
  const int n  = blockIdx.z;
  const int i0 = blockIdx.x * 2;   // two image rows per block
  const int t  = threadIdx.x;
  const int lane = t & 63, wid = t >> 6;
  const int wm = wid & 1, wn = wid >> 1;
  const int l16 = lane & 15, lg = lane >> 4;

  const __bf16* a_src = mmbf + ((size_t)n * CD + (t & 127)) * K7 + (t >> 7) * 8;

  const int b_sg  = t & 3;
  const int b_col = t >> 2;     // j within row
  const __bf16* b_src1 = xT + (((size_t)n * HD + i0) * XROW + b_col) * CD + b_sg * 8;
  const __bf16* b_src2 = b_src1 + (size_t)XROW * CD;
  const int bidx1 = (b_sg * 128 + (b_col ^ (b_sg * 4))) * 8;
  const int bidx2 = bidx1 + 64 * 8;

  const __bf16* xbn = xbf + (size_t)n * CD * SD;  // gather fallback

  int4 a0_0, a1_0, a0_1, a1_1;
  bf16x8 u0_0, u1_0, u0_1, u1_1;

#define OUT_ISSUE(ST, S) do {                                           \
    a0_##S = *(const int4*)(a_src + (ST) * 32);                         \
    a1_##S = *(const int4*)(a_src + (ST) * 32 + 16);                    \
    if constexpr (XTP) {                                                \
      u0_##S = *(const bf16x8*)(b_src1 + (ST) * 32);                    \
      u1_##S = *(const bf16x8*)(b_src2 + (ST) * 32);                    \
    } else {                                                            \
      _Pragma("unroll")                                                 \
      for (int e = 0; e < 8; ++e) {                                     \
        const int k_  = (ST) * 32 + b_sg * 8 + e;                       \
        const int q_  = k_ >> 7;                                        \
        const int c2_ = k_ & 127;                                       \
        const int jp_ = b_col + q_ - 3;                                 \
        const bool v_ = ((unsigned)jp_ < (unsigned)WD);                 \
        u0_##S[e] = v_ ? xbn[(size_t)c2_ * SD + i0 * WD + jp_] : (__bf16)0.f; \
        u1_##S[e] = v_ ? xbn[(size_t)c2_ * SD + (i0 + 1) * WD + jp_] : (__bf16)0.f; \
      }                                                                 \
    }                                                                   \
  } while (0)

#define OUT_STAGE(B, S) do {                                            \
    *(int4*)&As[B][(size_t)t * 8]         = a0_##S;                     \
    *(int4*)&As[B][(size_t)(t + 256) * 8] = a1_##S;                     \
    *(bf16x8*)&Bs[B][bidx1] = u0_##S;                                   \
    *(bf16x8*)&Bs[B][bidx2] = u1_##S;                                   \
  } while (0)

#define OUT_COMPUTE(B) do {                                             \
    bf16x8 af[4], bfr[4];                                               \
    _Pragma("unroll")                                                   \
    for (int fm = 0; fm < 4; ++fm)                                      \
      af[fm] = *(const bf16x8*)&As[B][(size_t)(lg * 128 + wm * 64 + fm * 16 + l16) * 8]; \
    _Pragma("unroll")                                                   \
    for (int fn = 0; fn < 4; ++fn)                                      \
      bfr[fn] = *(const bf16x8*)&Bs[B][(size_t)(lg * 128 + ((wn * 64 + fn * 16 + l16) ^ (lg * 4))) * 8]; \
    _Pragma("unroll")                                                   \
    for (int fm = 0; fm < 4; ++fm)                                      \
      _Pragma("unroll")                                                 \
      for (int fn = 0; fn < 4; ++fn)                                    \
        acc[fm][fn] = __builtin_amdgcn_mfma_f32_16x16x32_bf16(af[fm], bfr[fn], acc[fm][fn], 0, 0, 0); \
  } while (0)

  f32x4 acc[4][4] = {};
  OUT_ISSUE(0, 0); OUT_STAGE(0, 0); OUT_ISSUE(1, 1);
  const int NSTEP = K7 / 32;   // 28, even
  for (int st = 0; st < NSTEP; st += 2) {
    __syncthreads();
    if (st + 2 < NSTEP) OUT_ISSUE(st + 2, 0);
    OUT_COMPUTE(0);
    OUT_STAGE(1, 1);
    __syncthreads();
    if (st + 3 < NSTEP) OUT_ISSUE(st + 3, 1);
    OUT_COMPUTE(1);
    if (st + 2 < NSTEP) OUT_STAGE(0, 0);
  }
#undef OUT_ISSUE
#undef OUT_STAGE
#undef OUT_COMPUTE

  // epilogue: subtract depthwise t6, write out
  const float* xn = x + (size_t)n * CD * SD;
  const int i = i0 + wn;
#pragma unroll
  for (int fm = 0; fm < 4; ++fm)
#pragma unroll
    for (int r = 0; r < 4; ++r) {
      const int c = wm * 64 + fm * 16 + lg * 4 + r;
      const float w60 = w6[c * 3 + 0], w61 = w6[c * 3 + 1], w62 = w6[c * 3 + 2];
      const float* xc  = xn + (size_t)c * SD;
      const float* p4c = p4 + (size_t)c * SD;
#pragma unroll
      for (int fn = 0; fn < 4; ++fn) {
        const int j  = fn * 16 + l16;
        const int jm = (j - 1) & 63;
        float t6 = w61 * p4c[i * WD + jm] * xc[i * WD + jm];
        if (i >= 3)  t6 += w60 * p4c[(i - 3) * WD + jm] * xc[(i - 3) * WD + jm];
        if (i <= 60) t6 += w62 * p4c[(i + 3) * WD + jm] * xc[(i + 3) * WD + jm];
        outp[((size_t)(n * CD + c)) * SD + i * WD + j] = acc[fm][fn][r] - t6;
      }
    }
}

extern "C" void kernel_launch(void* const* d_in, const int* in_sizes, int n_in,
                              void* d_out, int out_size, void* d_ws, size_t ws_size,
                              hipStream_t stream) {
  const float* x  = (const float*)d_in[0];
  const float* p2 = (const float*)d_in[1];
  const float* p3 = (const float*)d_in[2];
  const float* p4 = (const float*)d_in[3];
  const float* w6 = (const float*)d_in[4];
  const float* w7 = (const float*)d_in[5];
  float* outp = (float*)d_out;

  const size_t elems_x  = (size_t)NB * CD * SD;   // 8,388,608
  const size_t elems_t8 = (size_t)NB * CD * K7;   // 1,835,008

  __bf16* xbf  = (__bf16*)d_ws;
  __bf16* t8bf = xbf  + elems_x;
  __bf16* mmbf = t8bf + elems_t8;
  __bf16* w7t  = mmbf + elems_t8;
  void*   region = (void*)(w7t + (size_t)K7 * K7);  // part / xT (disjoint phases)
  float*  part = (float*)region;
  __bf16* xT   = (__bf16*)region;

  const size_t base_bytes = (elems_x + 2 * elems_t8 + (size_t)K7 * K7) * 2;
  const size_t chunk      = elems_t8 * 4;
  const size_t xt_bytes   = (size_t)NB * HD * XROW * CD * 2;

  const bool split4 = ws_size >= base_bytes + 4 * chunk;
  const bool split2 = ws_size >= base_bytes + 2 * chunk;
  const bool use_xt = ws_size >= base_bytes + xt_bytes;

  dim3 blk(256);
  cvt_x_kernel<<<dim3((unsigned)(elems_x / (256 * 8))), blk, 0, stream>>>(x, xbf);
  w7t_kernel<<<dim3(14, 14), blk, 0, stream>>>(w7, w7t);

  if (split4) {
    t8_mfma<32, true><<<dim3(7, 4, NB), blk, 0, stream>>>(xbf, p2, p3, part, nullptr);
    reduce_scale<4><<<dim3((unsigned)(elems_t8 / 1024)), blk, 0, stream>>>(part, t8bf, 1.f / 64.f);
  } else if (split2) {
    t8_mfma<64, true><<<dim3(7, 2, NB), blk, 0, stream>>>(xbf, p2, p3, part, nullptr);
    reduce_scale<2><<<dim3((unsigned)(elems_t8 / 1024)), blk, 0, stream>>>(part, t8bf, 1.f / 64.f);
  } else {
    t8_mfma<128, false><<<dim3(7, 1, NB), blk, 0, stream>>>(xbf, p2, p3, nullptr, t8bf);
  }

  if (split2) {
    m_mfma<14, true><<<dim3(7, 16, 2), blk, 0, stream>>>(t8bf, w7t, part, nullptr);
    reduce_scale<2><<<dim3((unsigned)(elems_t8 / 1024)), blk, 0, stream>>>(part, mmbf, 0.033407655f);
  } else {
    m_mfma<28, false><<<dim3(7, 16, 1), blk, 0, stream>>>(t8bf, w7t, nullptr, mmbf);
  }

  if (use_xt) {
    xt_kernel<<<dim3(HD, NB), blk, 0, stream>>>(xbf, xT);
    out_mfma<true><<<dim3(HD / 2, 1, NB), blk, 0, stream>>>(x, xbf, xT, mmbf, p4, w6, outp);
  } else {
    out_mfma<false><<<dim3(HD / 2, 1, NB), blk, 0, stream>>>(x, xbf, nullptr, mmbf, p4, w6, outp);
  }
}